// Round 9
// baseline (945.534 us; speedup 1.0000x reference)
//
#include <hip/hip_runtime.h>
#include <float.h>

// MAM dense, fused. C[m,n] = max_k(A[m,k]*W[n,k]) + min_k + bias[n] + arg
// indices (numpy first-occurrence).
//
// R9 = R8 with the W DMA quad-stride fix. R8 wrote W quads {wv+4} at
// +4096B (A's quad stride: 64 rows x 16B) but W's quad stride is 2048B
// (128 rows x 16B) -> quads 4-7 never written, garbage read. Fix: +8192.
// DMA offsets must be derived from EACH region's own row count.
//
// R8 experiment (unchanged): on R5's 670us baseline, 256-thr blocks
// (R7 proved 512 loses residency):
//  - Tile 4 rows x 8 cols (BM=64, BN=128): per 16-k window the 16 A
//    fragments are HELD in registers and reused across 8 W columns ->
//    LDS reads/product 0.125 -> 0.094 (x0.75). All reads <=2-way banks.
//  - Window P=16 (2 windows/chunk): tracking cmp+csel amortized 2x ->
//    1.75 VALU inst/product. Ties keep earlier window = first occurrence;
//    within-window first occurrence via epilogue ascending 16-k rescan
//    from global (L2/L3-hot), bitwise-identical products (proven R3-R5).
//  - Quad-major LDS: per buf A [quad8][row64][4f] @0, W [quad8][row128][4f]
//    @8192; every ds_read address = base + compile-time imm. 48KB dbuf.
//  - DMA global_load_lds width=16, linear dest (rule 21): 6 issues/chunk.
//  - Spill canary: WRITE_SIZE >> 150MB.

typedef float f32x2 __attribute__((ext_vector_type(2)));
typedef float f32x4 __attribute__((ext_vector_type(4)));

#define BM 64
#define BN 128
#define BK 32

__device__ __forceinline__ f32x2 pk_mul(f32x2 a, f32x2 b) {
  f32x2 d;
  asm("v_pk_mul_f32 %0, %1, %2" : "=v"(d) : "v"(a), "v"(b));
  return d;
}
__device__ __forceinline__ float vmax3(float a, float b, float c) {
  float d;
  asm("v_max3_f32 %0, %1, %2, %3" : "=v"(d) : "v"(a), "v"(b), "v"(c));
  return d;
}
__device__ __forceinline__ float vmin3(float a, float b, float c) {
  float d;
  asm("v_min3_f32 %0, %1, %2, %3" : "=v"(d) : "v"(a), "v"(b), "v"(c));
  return d;
}

#define GLOAD16(gp, lp)                                                \
  __builtin_amdgcn_global_load_lds(                                    \
      (const __attribute__((address_space(1))) unsigned int*)(gp),     \
      (__attribute__((address_space(3))) unsigned int*)(lp), 16, 0, 0)

__global__ __launch_bounds__(256)
void mam_fused(const float* __restrict__ A, const float* __restrict__ W,
               const float* __restrict__ bias,
               float* __restrict__ out_v, float* __restrict__ out_ax,
               float* __restrict__ out_an, int M, int N, int K) {
  // per buf: A [quad8][row64][4f] = 8192B @0, W [quad8][row128][4f] =
  // 16384B @8192. buf stride 24576B; total 49152B.
  __shared__ __align__(16) unsigned char pool[49152];

  const int tid = threadIdx.x;
  const int tx = tid & 15;  // n-group: cols tx + 16j, j=0..7
  const int ty = tid >> 4;  // m-group: rows ty*4 .. ty*4+3  (ty 0..15)
  const int m0 = blockIdx.y * BM;
  const int n0 = blockIdx.x * BN;

  // ---- DMA mapping: wave wv; lane ln = row; quads {wv, wv+4} ----
  const int wv = tid >> 6;  // 0..3
  const int ln = tid & 63;
  int grA = m0 + ln;       grA = grA < M ? grA : M - 1;
  int grW0 = n0 + ln;      grW0 = grW0 < N ? grW0 : N - 1;
  int grW1 = n0 + 64 + ln; grW1 = grW1 < N ? grW1 : N - 1;
  const float* pA = A + (size_t)grA * K + wv * 4;
  const float* pW0 = W + (size_t)grW0 * K + wv * 4;
  const float* pW1 = W + (size_t)grW1 * K + wv * 4;
  const unsigned dmaA = (unsigned)wv * 1024u;           // A quad stride 1024B
  const unsigned dmaW = 8192u + (unsigned)wv * 2048u;   // W quad stride 2048B

#define ISSUE(CH, BUF)                                                 \
  {                                                                    \
    const int _kk = (CH)*BK;                                           \
    unsigned char* _b = pool + (BUF)*24576u;                           \
    GLOAD16(pA + _kk, _b + dmaA);                 /* A quad wv   */    \
    GLOAD16(pA + _kk + 16, _b + dmaA + 4096u);    /* A quad wv+4 */    \
    GLOAD16(pW0 + _kk, _b + dmaW);                /* W quad wv rows 0-63 */ \
    GLOAD16(pW1 + _kk, _b + dmaW + 1024u);        /* W quad wv rows 64-127 */ \
    GLOAD16(pW0 + _kk + 16, _b + dmaW + 8192u);   /* W quad wv+4 rows 0-63 */ \
    GLOAD16(pW1 + _kk + 16, _b + dmaW + 9216u);   /* W quad wv+4 rows 64-127 */ \
  }

  // ---- accumulators ----
  float vmax[4][8], vmin[4][8];
  int pmax[4][8], pmin[4][8];  // 16-k window of first occurrence (0..63)
#pragma unroll
  for (int i = 0; i < 4; ++i)
#pragma unroll
    for (int j = 0; j < 8; ++j) {
      vmax[i][j] = -FLT_MAX;
      vmin[i][j] = FLT_MAX;
      pmax[i][j] = 0;
      pmin[i][j] = 0;
    }

  const int nchunk = K / BK;

  // ---- main loop: DMA double-buffered, one barrier per chunk ----
  ISSUE(0, 0)
  __syncthreads();
  int buf = 0;
  for (int ch = 0; ch < nchunk; ++ch) {
    if (ch + 1 < nchunk) ISSUE(ch + 1, buf ^ 1)
    const unsigned char* Ab = pool + (unsigned)buf * 24576u + ty * 64;
    const unsigned char* Wb = pool + (unsigned)buf * 24576u + 8192u + tx * 16;
#pragma unroll
    for (int w = 0; w < 2; ++w) {  // 16-k window: quads 4w..4w+3
      const int wnd = ch * 2 + w;
      f32x4 a[4][4];  // [q][i], held across all 8 j
#pragma unroll
      for (int q = 0; q < 4; ++q)
#pragma unroll
        for (int i = 0; i < 4; ++i)
          a[q][i] = *(const f32x4*)(Ab + (4 * w + q) * 1024 + i * 16);
#pragma unroll
      for (int j = 0; j < 8; ++j) {
        const f32x4 w0 = *(const f32x4*)(Wb + (4 * w + 0) * 2048 + j * 256);
        const f32x4 w1 = *(const f32x4*)(Wb + (4 * w + 1) * 2048 + j * 256);
        const f32x4 w2 = *(const f32x4*)(Wb + (4 * w + 2) * 2048 + j * 256);
        const f32x4 w3 = *(const f32x4*)(Wb + (4 * w + 3) * 2048 + j * 256);
#pragma unroll
        for (int i = 0; i < 4; ++i) {
          f32x2 q0 = pk_mul(a[0][i].xy, w0.xy);
          f32x2 q1 = pk_mul(a[0][i].zw, w0.zw);
          float c = vmax3(vmax[i][j], q0.x, q0.y);
          float d = vmin3(vmin[i][j], q0.x, q0.y);
          c = vmax3(c, q1.x, q1.y);
          d = vmin3(d, q1.x, q1.y);
          q0 = pk_mul(a[1][i].xy, w1.xy);
          q1 = pk_mul(a[1][i].zw, w1.zw);
          c = vmax3(c, q0.x, q0.y);
          d = vmin3(d, q0.x, q0.y);
          c = vmax3(c, q1.x, q1.y);
          d = vmin3(d, q1.x, q1.y);
          q0 = pk_mul(a[2][i].xy, w2.xy);
          q1 = pk_mul(a[2][i].zw, w2.zw);
          c = vmax3(c, q0.x, q0.y);
          d = vmin3(d, q0.x, q0.y);
          c = vmax3(c, q1.x, q1.y);
          d = vmin3(d, q1.x, q1.y);
          q0 = pk_mul(a[3][i].xy, w3.xy);
          q1 = pk_mul(a[3][i].zw, w3.zw);
          c = vmax3(c, q0.x, q0.y);
          d = vmin3(d, q0.x, q0.y);
          c = vmax3(c, q1.x, q1.y);
          d = vmin3(d, q1.x, q1.y);
          pmax[i][j] = (c != vmax[i][j]) ? wnd : pmax[i][j];
          vmax[i][j] = c;
          pmin[i][j] = (d != vmin[i][j]) ? wnd : pmin[i][j];
          vmin[i][j] = d;
        }
      }
    }
    __syncthreads();
    buf ^= 1;
  }

  // ---- epilogue: values + within-window argmax from global (L2/L3-hot) ----
#pragma unroll
  for (int i = 0; i < 4; ++i) {
    const int gm = m0 + ty * 4 + i;
    if (gm >= M) continue;
    const size_t arow = (size_t)gm * K;
#pragma unroll
    for (int j = 0; j < 8; ++j) {
      const int gn = n0 + tx + 16 * j;
      if (gn >= N) continue;
      const size_t wrow = (size_t)gn * K;
      const size_t base = (size_t)gm * N + gn;
      out_v[base] = vmax[i][j] + vmin[i][j] + bias[gn];
      {  // max side: ascending scan of the winning 16-k window
        const int kb = pmax[i][j] * 16;
        const float* ap = A + arow + kb;
        const float* wp = W + wrow + kb;
        float cur = -FLT_MAX;
        int pos = 0;
#pragma unroll
        for (int g = 0; g < 4; ++g) {
          const f32x4 av = *(const f32x4*)(ap + g * 4);
          const f32x4 wvv = *(const f32x4*)(wp + g * 4);
          float p;
          p = av.x * wvv.x; if (p > cur) { cur = p; pos = g * 4 + 0; }
          p = av.y * wvv.y; if (p > cur) { cur = p; pos = g * 4 + 1; }
          p = av.z * wvv.z; if (p > cur) { cur = p; pos = g * 4 + 2; }
          p = av.w * wvv.w; if (p > cur) { cur = p; pos = g * 4 + 3; }
        }
        out_ax[base] = (float)(kb + pos);
      }
      {  // min side
        const int kb = pmin[i][j] * 16;
        const float* ap = A + arow + kb;
        const float* wp = W + wrow + kb;
        float cur = FLT_MAX;
        int pos = 0;
#pragma unroll
        for (int g = 0; g < 4; ++g) {
          const f32x4 av = *(const f32x4*)(ap + g * 4);
          const f32x4 wvv = *(const f32x4*)(wp + g * 4);
          float p;
          p = av.x * wvv.x; if (p < cur) { cur = p; pos = g * 4 + 0; }
          p = av.y * wvv.y; if (p < cur) { cur = p; pos = g * 4 + 1; }
          p = av.z * wvv.z; if (p < cur) { cur = p; pos = g * 4 + 2; }
          p = av.w * wvv.w; if (p < cur) { cur = p; pos = g * 4 + 3; }
        }
        out_an[base] = (float)(kb + pos);
      }
    }
  }
}

extern "C" void kernel_launch(void* const* d_in, const int* in_sizes, int n_in,
                              void* d_out, int out_size, void* d_ws, size_t ws_size,
                              hipStream_t stream) {
  const float* A = (const float*)d_in[0];     // [M, K] fp32
  const float* W = (const float*)d_in[1];     // [N, K] fp32
  const float* bias = (const float*)d_in[2];  // [N]    fp32
  const int N = in_sizes[2];
  const int K = in_sizes[1] / N;
  const int M = in_sizes[0] / K;
  float* out_v = (float*)d_out;
  float* out_ax = out_v + (size_t)M * N;
  float* out_an = out_v + 2 * (size_t)M * N;
  dim3 grid((N + BN - 1) / BN, (M + BM - 1) / BM);
  mam_fused<<<grid, dim3(256), 0, stream>>>(A, W, bias, out_v, out_ax, out_an,
                                            M, N, K);
}